// Round 3
// baseline (587.285 us; speedup 1.0000x reference)
//
#include <hip/hip_runtime.h>

typedef unsigned short u16;
typedef unsigned int u32;
typedef __attribute__((ext_vector_type(8))) short short8;
typedef __attribute__((ext_vector_type(4))) short short4v;
typedef __attribute__((ext_vector_type(4))) float f32x4;

__device__ __forceinline__ u16 f2bf(float f) {
  union { float f; u32 u; } v; v.f = f;
  u32 u = v.u;
  u32 r = (u + 0x7fffu + ((u >> 16) & 1u)) >> 16;
  return (u16)r;
}
__device__ __forceinline__ float bf2f(u16 u) {
  union { u32 u; float f; } v; v.u = ((u32)u) << 16;
  return v.f;
}

// ---- q conversion: fp32 (B,S,Dm) * mask(B,S,1) -> bf16, 4 elems/thread ----
__global__ __launch_bounds__(256) void conv_q(const float* __restrict__ q,
                                              const float* __restrict__ qm,
                                              u16* __restrict__ dst) {
  int i = (blockIdx.x * 256 + threadIdx.x) * 4;  // < 8388608
  float m = qm[i >> 10];
  float4 v = *(const float4*)(q + i);
  short4v o;
  o.x = (short)f2bf(v.x * m);
  o.y = (short)f2bf(v.y * m);
  o.z = (short)f2bf(v.z * m);
  o.w = (short)f2bf(v.w * m);
  *(short4v*)(dst + i) = o;
}

// ---- k/v slice rows [1920,2048) per batch + mask + convert -> (512,1024) bf16 ----
__global__ __launch_bounds__(256) void conv_kv_slice(const float* __restrict__ src,
                                                     const float* __restrict__ mask,
                                                     u16* __restrict__ dst) {
  int i = (blockIdx.x * 256 + threadIdx.x) * 4;  // < 524288
  int r = i >> 10, c = i & 1023;
  size_t sr = (size_t)(r >> 7) * 2048 + 1920 + (r & 127);
  float m = mask[sr];
  float4 v = *(const float4*)(src + sr * 1024 + c);
  short4v o;
  o.x = (short)f2bf(v.x * m);
  o.y = (short)f2bf(v.y * m);
  o.z = (short)f2bf(v.z * m);
  o.w = (short)f2bf(v.w * m);
  *(short4v*)(dst + i) = o;
}

// ---- weight transpose + convert: WT[n][k] = bf16(W[k][n]), 1024x1024 ----
__global__ __launch_bounds__(256) void transpose_w(const float* __restrict__ W,
                                                   u16* __restrict__ WT) {
  __shared__ u16 tile[32][33];
  int tx = threadIdx.x, ty = threadIdx.y;
  int x = blockIdx.x * 32 + tx;
  int y0 = blockIdx.y * 32;
  for (int i = ty; i < 32; i += 8)
    tile[i][tx] = f2bf(W[(size_t)(y0 + i) * 1024 + x]);
  __syncthreads();
  int x2 = y0 + tx;
  int r0 = blockIdx.x * 32;
  for (int i = ty; i < 32; i += 8)
    WT[(size_t)(r0 + i) * 1024 + x2] = tile[tx][i];
}

// C[r][c] = (A[r] @ BT[c]^T) + bias[c]
// OUTMODE 0: bf16 r*N+c ; 1: bf16 FK (b,h,l,d) ; 2: bf16 FVT (b,h,d,l) ;
// OUTMODE 3: fp32 r*N+c (final output)
template <int OUTMODE>
__global__ __launch_bounds__(256) void gemm_bt(
    const u16* __restrict__ A, const u16* __restrict__ BT,
    const float* __restrict__ bias, void* __restrict__ Cv, int N, int K) {
  const int wave = threadIdx.x >> 6, lane = threadIdx.x & 63;
  const int ln = lane & 15, quad = lane >> 4;
  const int row0 = blockIdx.x * 64 + wave * 16;
  const int col0 = blockIdx.y * 64;
  const u16* ap = A + (size_t)(row0 + ln) * K + quad * 8;
  const u16* bp = BT + (size_t)(col0 + ln) * K + quad * 8;
  f32x4 acc0 = {0.f, 0.f, 0.f, 0.f}, acc1 = acc0, acc2 = acc0, acc3 = acc0;
  for (int k0 = 0; k0 < K; k0 += 32) {
    short8 a = *(const short8*)(ap + k0);
    short8 b0 = *(const short8*)(bp + k0);
    short8 b1 = *(const short8*)(bp + 16 * K + k0);
    short8 b2 = *(const short8*)(bp + 32 * K + k0);
    short8 b3 = *(const short8*)(bp + 48 * K + k0);
    acc0 = __builtin_amdgcn_mfma_f32_16x16x32_bf16(a, b0, acc0, 0, 0, 0);
    acc1 = __builtin_amdgcn_mfma_f32_16x16x32_bf16(a, b1, acc1, 0, 0, 0);
    acc2 = __builtin_amdgcn_mfma_f32_16x16x32_bf16(a, b2, acc2, 0, 0, 0);
    acc3 = __builtin_amdgcn_mfma_f32_16x16x32_bf16(a, b3, acc3, 0, 0, 0);
  }
  f32x4 accs[4] = {acc0, acc1, acc2, acc3};
  for (int nt = 0; nt < 4; ++nt) {
    int c = col0 + nt * 16 + ln;
    float bval = bias ? bias[c] : 0.f;
    for (int reg = 0; reg < 4; ++reg) {
      int r = row0 + quad * 4 + reg;
      float val = accs[nt][reg] + bval;
      if (OUTMODE == 3) {
        ((float*)Cv)[(size_t)r * N + c] = val;
      } else {
        size_t idx;
        if (OUTMODE == 0)
          idx = (size_t)r * N + c;
        else if (OUTMODE == 1)
          idx = ((size_t)(r >> 7) << 17) + ((size_t)(c >> 6) << 13) +
                ((size_t)(r & 127) << 6) + (c & 63);
        else
          idx = ((size_t)(r >> 7) << 17) + ((size_t)(c >> 6) << 13) +
                ((size_t)(c & 63) << 7) + (r & 127);
        ((u16*)Cv)[idx] = f2bf(val);
      }
    }
  }
}

// Fused attention: per (b,h) and 16-row Q tile (4 tiles/block).
__global__ __launch_bounds__(256) void attn_kernel(
    const u16* __restrict__ Q, const u16* __restrict__ FK,
    const u16* __restrict__ FVT, float* __restrict__ attn_out,
    u16* __restrict__ OUTP) {
  __shared__ float lds[4][16 * 128];
  const int wave = threadIdx.x >> 6, lane = threadIdx.x & 63;
  const int ln = lane & 15, quad = lane >> 4;
  const int bh = blockIdx.x, b = bh >> 4, h = bh & 15;
  const int q0 = blockIdx.y * 64 + wave * 16;

  const u16* qp = Q + (size_t)(b * 2048 + q0 + ln) * 1024 + h * 64 + quad * 8;
  const u16* fk = FK + ((size_t)bh << 13);
  const u16* fvt = FVT + ((size_t)bh << 13);

  f32x4 acc[8];
  for (int i = 0; i < 8; ++i) acc[i] = f32x4{0.f, 0.f, 0.f, 0.f};
  for (int ks = 0; ks < 2; ++ks) {
    short8 a = *(const short8*)(qp + ks * 32);
    for (int nt = 0; nt < 8; ++nt) {
      short8 bfrag = *(const short8*)(fk + (size_t)(nt * 16 + ln) * 64 +
                                      ks * 32 + quad * 8);
      acc[nt] = __builtin_amdgcn_mfma_f32_16x16x32_bf16(a, bfrag, acc[nt], 0, 0, 0);
    }
  }
  float mx[4] = {-3e38f, -3e38f, -3e38f, -3e38f};
  for (int nt = 0; nt < 8; ++nt) {
    int l = nt * 16 + ln;
    for (int reg = 0; reg < 4; ++reg) {
      int qg = q0 + quad * 4 + reg;
      float vv = acc[nt][reg] * 0.125f;
      if (l > qg) vv = -1e9f;
      acc[nt][reg] = vv;
      mx[reg] = fmaxf(mx[reg], vv);
    }
  }
  for (int off = 1; off < 16; off <<= 1)
    for (int reg = 0; reg < 4; ++reg)
      mx[reg] = fmaxf(mx[reg], __shfl_xor(mx[reg], off, 64));
  float sm[4] = {0.f, 0.f, 0.f, 0.f};
  for (int nt = 0; nt < 8; ++nt)
    for (int reg = 0; reg < 4; ++reg) {
      float p = __expf(acc[nt][reg] - mx[reg]);
      acc[nt][reg] = p;
      sm[reg] += p;
    }
  for (int off = 1; off < 16; off <<= 1)
    for (int reg = 0; reg < 4; ++reg) sm[reg] += __shfl_xor(sm[reg], off, 64);
  float inv[4];
  for (int reg = 0; reg < 4; ++reg) inv[reg] = 1.f / sm[reg];
  for (int nt = 0; nt < 8; ++nt)
    for (int reg = 0; reg < 4; ++reg)
      lds[wave][(quad * 4 + reg) * 128 + nt * 16 + ln] = acc[nt][reg] * inv[reg];
  __syncthreads();
  // attn output (fp32): lane -> row lane>>2, 32-col block (lane&3)*32
  {
    int r = lane >> 2, cb = (lane & 3) * 32;
    const float* lrow = &lds[wave][r * 128 + cb];
    float* dst = attn_out + ((size_t)bh * 2048 + q0 + r) * 128 + cb;
    for (int vblk = 0; vblk < 8; ++vblk)
      *(float4*)(dst + vblk * 4) = *(const float4*)(lrow + vblk * 4);
  }
  // PV: out(16x64) = P(16x128) @ FV(128x64); A from LDS (bf16 repack), B = FVT[d][l]
  f32x4 o[4];
  for (int i = 0; i < 4; ++i) o[i] = f32x4{0.f, 0.f, 0.f, 0.f};
  for (int kk = 0; kk < 4; ++kk) {
    const float* apf = &lds[wave][ln * 128 + kk * 32 + quad * 8];
    short8 a;
    for (int j = 0; j < 8; ++j) a[j] = (short)f2bf(apf[j]);
    for (int nt = 0; nt < 4; ++nt) {
      short8 bfrag = *(const short8*)(fvt + (size_t)(nt * 16 + ln) * 128 +
                                      kk * 32 + quad * 8);
      o[nt] = __builtin_amdgcn_mfma_f32_16x16x32_bf16(a, bfrag, o[nt], 0, 0, 0);
    }
  }
  for (int nt = 0; nt < 4; ++nt)
    for (int reg = 0; reg < 4; ++reg) {
      int r = q0 + quad * 4 + reg;
      int c = h * 64 + nt * 16 + ln;
      OUTP[(size_t)(b * 2048 + r) * 1024 + c] = f2bf(o[nt][reg]);
    }
}

extern "C" void kernel_launch(void* const* d_in, const int* in_sizes, int n_in,
                              void* d_out, int out_size, void* d_ws,
                              size_t ws_size, hipStream_t stream) {
  const float* q = (const float*)d_in[0];
  const float* k = (const float*)d_in[1];
  const float* v = (const float*)d_in[2];
  const float* qm = (const float*)d_in[3];
  const float* km = (const float*)d_in[4];
  const float* vm = (const float*)d_in[5];
  const float* wq = (const float*)d_in[6];
  const float* bq = (const float*)d_in[7];
  const float* wk = (const float*)d_in[8];
  const float* bk = (const float*)d_in[9];
  const float* wv = (const float*)d_in[10];
  const float* bv = (const float*)d_in[11];
  const float* wo = (const float*)d_in[12];
  const float* bo = (const float*)d_in[13];
  float* out = (float*)d_out;                          // (4,2048,1024) fp32
  float* attn_out = out + (size_t)4 * 2048 * 1024;     // (4,16,2048,128) fp32

  char* ws = (char*)d_ws;
  const size_t MB = 1ull << 20;
  u16* WqT = (u16*)(ws + 0 * MB);    // 2 MB each (bf16 1024x1024, transposed)
  u16* WkT = (u16*)(ws + 2 * MB);
  u16* WvT = (u16*)(ws + 4 * MB);
  u16* WoT = (u16*)(ws + 6 * MB);
  u16* Qws = (u16*)(ws + 8 * MB);    // 16 MB projected Q (B,S,Dm) bf16
  u16* FKw = (u16*)(ws + 24 * MB);   // 1 MB (b,h,l,d) bf16
  u16* FVTw = (u16*)(ws + 25 * MB);  // 1 MB (b,h,d,l) bf16
  u16* OUTP = (u16*)(ws + 26 * MB);  // 16 MB pre-Wo bf16; aliased as Qc first
  u16* Qc = OUTP;                    // masked+converted q (dead before OUTP written)
  u16* Kc = (u16*)(ws + 42 * MB);    // 1 MB sliced+masked k
  u16* Vc = (u16*)(ws + 43 * MB);    // 1 MB sliced+masked v

  conv_q<<<8192, 256, 0, stream>>>(q, qm, Qc);
  conv_kv_slice<<<512, 256, 0, stream>>>(k, km, Kc);
  conv_kv_slice<<<512, 256, 0, stream>>>(v, vm, Vc);

  dim3 tb(32, 8), tg(32, 32);
  transpose_w<<<tg, tb, 0, stream>>>(wq, WqT);
  transpose_w<<<tg, tb, 0, stream>>>(wk, WkT);
  transpose_w<<<tg, tb, 0, stream>>>(wv, WvT);
  transpose_w<<<tg, tb, 0, stream>>>(wo, WoT);

  // Q projection: full 8192 rows -> bf16 Qws
  gemm_bt<0><<<dim3(128, 16), 256, 0, stream>>>(Qc, WqT, bq, Qws, 1024, 1024);
  // K/V projections on the pre-sliced 512 rows
  gemm_bt<1><<<dim3(8, 16), 256, 0, stream>>>(Kc, WkT, bk, FKw, 1024, 1024);
  gemm_bt<2><<<dim3(8, 16), 256, 0, stream>>>(Vc, WvT, bv, FVTw, 1024, 1024);
  attn_kernel<<<dim3(64, 32), 256, 0, stream>>>(Qws, FKw, FVTw, attn_out, OUTP);
  // Output projection -> fp32 output 0
  gemm_bt<3><<<dim3(128, 16), 256, 0, stream>>>(OUTP, WoT, bo, out, 1024, 1024);
}

// Round 4
// 359.443 us; speedup vs baseline: 1.6339x; 1.6339x over previous
//
#include <hip/hip_runtime.h>

typedef unsigned short u16;
typedef unsigned int u32;
typedef __attribute__((ext_vector_type(8))) short short8;
typedef __attribute__((ext_vector_type(4))) short short4v;
typedef __attribute__((ext_vector_type(4))) float f32x4;

__device__ __forceinline__ u16 f2bf(float f) {
  union { float f; u32 u; } v; v.f = f;
  u32 u = v.u;
  u32 r = (u + 0x7fffu + ((u >> 16) & 1u)) >> 16;
  return (u16)r;
}

// async global->LDS, 16 B per lane; lds base must be wave-uniform,
// lane i lands at lds + i*16 bytes.
__device__ __forceinline__ void async_ld16(const u16* g, u16* l) {
  __builtin_amdgcn_global_load_lds(
      (const __attribute__((address_space(1))) void*)g,
      (__attribute__((address_space(3))) void*)l, 16, 0, 0);
}

// ---- q conversion: fp32 (B,S,Dm) * mask(B,S,1) -> bf16 ----
__global__ __launch_bounds__(256) void conv_q(const float* __restrict__ q,
                                              const float* __restrict__ qm,
                                              u16* __restrict__ dst) {
  int i = (blockIdx.x * 256 + threadIdx.x) * 4;
  float m = qm[i >> 10];
  float4 v = *(const float4*)(q + i);
  short4v o;
  o.x = (short)f2bf(v.x * m);
  o.y = (short)f2bf(v.y * m);
  o.z = (short)f2bf(v.z * m);
  o.w = (short)f2bf(v.w * m);
  *(short4v*)(dst + i) = o;
}

// ---- k/v slice rows [1920,2048) per batch + mask + convert ----
__global__ __launch_bounds__(256) void conv_kv_slice(const float* __restrict__ src,
                                                     const float* __restrict__ mask,
                                                     u16* __restrict__ dst) {
  int i = (blockIdx.x * 256 + threadIdx.x) * 4;
  int r = i >> 10, c = i & 1023;
  size_t sr = (size_t)(r >> 7) * 2048 + 1920 + (r & 127);
  float m = mask[sr];
  float4 v = *(const float4*)(src + sr * 1024 + c);
  short4v o;
  o.x = (short)f2bf(v.x * m);
  o.y = (short)f2bf(v.y * m);
  o.z = (short)f2bf(v.z * m);
  o.w = (short)f2bf(v.w * m);
  *(short4v*)(dst + i) = o;
}

// ---- weight transpose + convert: WT[n][k] = bf16(W[k][n]) ----
__global__ __launch_bounds__(256) void transpose_w(const float* __restrict__ W,
                                                   u16* __restrict__ WT) {
  __shared__ u16 tile[32][33];
  int tx = threadIdx.x, ty = threadIdx.y;
  int x = blockIdx.x * 32 + tx;
  int y0 = blockIdx.y * 32;
  for (int i = ty; i < 32; i += 8)
    tile[i][tx] = f2bf(W[(size_t)(y0 + i) * 1024 + x]);
  __syncthreads();
  int x2 = y0 + tx;
  int r0 = blockIdx.x * 32;
  for (int i = ty; i < 32; i += 8)
    WT[(size_t)(r0 + i) * 1024 + x2] = tile[tx][i];
}

// ---- m97-style 128x128 tiled GEMM: C = A @ BT^T + bias ----
// A [M x K] bf16 row-major, BT [N x K] bf16 row-major (K-contiguous both).
// OUTMODE 0: bf16 C[r*N+c] ; OUTMODE 3: fp32 C[r*N+c]
template <int OUTMODE>
__global__ __launch_bounds__(256) void gemm_tile(
    const u16* __restrict__ A, const u16* __restrict__ BT,
    const float* __restrict__ bias, void* __restrict__ Cv, int N, int K) {
  __shared__ u16 As[128 * 32];  // [row][k] row-major, BK=32
  __shared__ u16 Bs[128 * 32];  // [col][k]
  const int wave = threadIdx.x >> 6, lane = threadIdx.x & 63;
  const int ln = lane & 15, quad = lane >> 4;
  const int w0 = wave & 1, w1 = wave >> 1;  // col half / row half
  const int row0 = blockIdx.x * 128;
  const int col0 = blockIdx.y * 128;
  // staging: lane -> (row lane>>2, cols (lane&3)*8..+8); wave stages rows
  // [wave*32, wave*32+32) of both tiles, 16 rows per instruction.
  const int srow = lane >> 2, scol = (lane & 3) * 8;
  const u16* gA = A + (size_t)(row0 + wave * 32 + srow) * K + scol;
  const u16* gB = BT + (size_t)(col0 + wave * 32 + srow) * K + scol;
  u16* lA = &As[(wave * 32) * 32];
  u16* lB = &Bs[(wave * 32) * 32];

  f32x4 acc[4][4];
  for (int i = 0; i < 4; ++i)
    for (int j = 0; j < 4; ++j) acc[i][j] = f32x4{0.f, 0.f, 0.f, 0.f};

  for (int k0 = 0; k0 < K; k0 += 32) {
    async_ld16(gA + k0, lA);
    async_ld16(gA + (size_t)16 * K + k0, lA + 16 * 32);
    async_ld16(gB + k0, lB);
    async_ld16(gB + (size_t)16 * K + k0, lB + 16 * 32);
    __syncthreads();
    short8 af[4], bf[4];
    for (int mt = 0; mt < 4; ++mt)
      af[mt] = *(const short8*)&As[(w1 * 64 + mt * 16 + ln) * 32 + quad * 8];
    for (int nt = 0; nt < 4; ++nt)
      bf[nt] = *(const short8*)&Bs[(w0 * 64 + nt * 16 + ln) * 32 + quad * 8];
    for (int mt = 0; mt < 4; ++mt)
      for (int nt = 0; nt < 4; ++nt)
        acc[mt][nt] =
            __builtin_amdgcn_mfma_f32_16x16x32_bf16(af[mt], bf[nt], acc[mt][nt], 0, 0, 0);
    __syncthreads();
  }

  for (int nt = 0; nt < 4; ++nt) {
    int c = col0 + w0 * 64 + nt * 16 + ln;
    float bval = bias ? bias[c] : 0.f;
    for (int mt = 0; mt < 4; ++mt)
      for (int reg = 0; reg < 4; ++reg) {
        int r = row0 + w1 * 64 + mt * 16 + quad * 4 + reg;
        float val = acc[mt][nt][reg] + bval;
        if (OUTMODE == 3)
          ((float*)Cv)[(size_t)r * N + c] = val;
        else
          ((u16*)Cv)[(size_t)r * N + c] = f2bf(val);
      }
  }
}

// ---- small GEMM (per-wave 16x64 tile, direct loads) for K/V projections ----
// OUTMODE 1: bf16 FK (b,h,l,d) ; 2: bf16 FVT (b,h,d,l)
template <int OUTMODE>
__global__ __launch_bounds__(256) void gemm_bt(
    const u16* __restrict__ A, const u16* __restrict__ BT,
    const float* __restrict__ bias, void* __restrict__ Cv, int N, int K) {
  const int wave = threadIdx.x >> 6, lane = threadIdx.x & 63;
  const int ln = lane & 15, quad = lane >> 4;
  const int row0 = blockIdx.x * 64 + wave * 16;
  const int col0 = blockIdx.y * 64;
  const u16* ap = A + (size_t)(row0 + ln) * K + quad * 8;
  const u16* bp = BT + (size_t)(col0 + ln) * K + quad * 8;
  f32x4 acc0 = {0.f, 0.f, 0.f, 0.f}, acc1 = acc0, acc2 = acc0, acc3 = acc0;
  for (int k0 = 0; k0 < K; k0 += 32) {
    short8 a = *(const short8*)(ap + k0);
    short8 b0 = *(const short8*)(bp + k0);
    short8 b1 = *(const short8*)(bp + 16 * K + k0);
    short8 b2 = *(const short8*)(bp + 32 * K + k0);
    short8 b3 = *(const short8*)(bp + 48 * K + k0);
    acc0 = __builtin_amdgcn_mfma_f32_16x16x32_bf16(a, b0, acc0, 0, 0, 0);
    acc1 = __builtin_amdgcn_mfma_f32_16x16x32_bf16(a, b1, acc1, 0, 0, 0);
    acc2 = __builtin_amdgcn_mfma_f32_16x16x32_bf16(a, b2, acc2, 0, 0, 0);
    acc3 = __builtin_amdgcn_mfma_f32_16x16x32_bf16(a, b3, acc3, 0, 0, 0);
  }
  f32x4 accs[4] = {acc0, acc1, acc2, acc3};
  for (int nt = 0; nt < 4; ++nt) {
    int c = col0 + nt * 16 + ln;
    float bval = bias ? bias[c] : 0.f;
    for (int reg = 0; reg < 4; ++reg) {
      int r = row0 + quad * 4 + reg;
      float val = accs[nt][reg] + bval;
      size_t idx;
      if (OUTMODE == 1)
        idx = ((size_t)(r >> 7) << 17) + ((size_t)(c >> 6) << 13) +
              ((size_t)(r & 127) << 6) + (c & 63);
      else
        idx = ((size_t)(r >> 7) << 17) + ((size_t)(c >> 6) << 13) +
              ((size_t)(c & 63) << 7) + (r & 127);
      ((u16*)Cv)[idx] = f2bf(val);
    }
  }
}

// Fused attention: per (b,h) and 16-row Q tile (4 tiles/block).
__global__ __launch_bounds__(256) void attn_kernel(
    const u16* __restrict__ Q, const u16* __restrict__ FK,
    const u16* __restrict__ FVT, float* __restrict__ attn_out,
    u16* __restrict__ OUTP) {
  __shared__ float lds[4][16 * 128];
  const int wave = threadIdx.x >> 6, lane = threadIdx.x & 63;
  const int ln = lane & 15, quad = lane >> 4;
  const int bh = blockIdx.x, b = bh >> 4, h = bh & 15;
  const int q0 = blockIdx.y * 64 + wave * 16;

  const u16* qp = Q + (size_t)(b * 2048 + q0 + ln) * 1024 + h * 64 + quad * 8;
  const u16* fk = FK + ((size_t)bh << 13);
  const u16* fvt = FVT + ((size_t)bh << 13);

  f32x4 acc[8];
  for (int i = 0; i < 8; ++i) acc[i] = f32x4{0.f, 0.f, 0.f, 0.f};
  for (int ks = 0; ks < 2; ++ks) {
    short8 a = *(const short8*)(qp + ks * 32);
    for (int nt = 0; nt < 8; ++nt) {
      short8 bfrag = *(const short8*)(fk + (size_t)(nt * 16 + ln) * 64 +
                                      ks * 32 + quad * 8);
      acc[nt] = __builtin_amdgcn_mfma_f32_16x16x32_bf16(a, bfrag, acc[nt], 0, 0, 0);
    }
  }
  float mx[4] = {-3e38f, -3e38f, -3e38f, -3e38f};
  for (int nt = 0; nt < 8; ++nt) {
    int l = nt * 16 + ln;
    for (int reg = 0; reg < 4; ++reg) {
      int qg = q0 + quad * 4 + reg;
      float vv = acc[nt][reg] * 0.125f;
      if (l > qg) vv = -1e9f;
      acc[nt][reg] = vv;
      mx[reg] = fmaxf(mx[reg], vv);
    }
  }
  for (int off = 1; off < 16; off <<= 1)
    for (int reg = 0; reg < 4; ++reg)
      mx[reg] = fmaxf(mx[reg], __shfl_xor(mx[reg], off, 64));
  float sm[4] = {0.f, 0.f, 0.f, 0.f};
  for (int nt = 0; nt < 8; ++nt)
    for (int reg = 0; reg < 4; ++reg) {
      float p = __expf(acc[nt][reg] - mx[reg]);
      acc[nt][reg] = p;
      sm[reg] += p;
    }
  for (int off = 1; off < 16; off <<= 1)
    for (int reg = 0; reg < 4; ++reg) sm[reg] += __shfl_xor(sm[reg], off, 64);
  float inv[4];
  for (int reg = 0; reg < 4; ++reg) inv[reg] = 1.f / sm[reg];
  for (int nt = 0; nt < 8; ++nt)
    for (int reg = 0; reg < 4; ++reg)
      lds[wave][(quad * 4 + reg) * 128 + nt * 16 + ln] = acc[nt][reg] * inv[reg];
  __syncthreads();
  {
    int r = lane >> 2, cb = (lane & 3) * 32;
    const float* lrow = &lds[wave][r * 128 + cb];
    float* dst = attn_out + ((size_t)bh * 2048 + q0 + r) * 128 + cb;
    for (int vblk = 0; vblk < 8; ++vblk)
      *(float4*)(dst + vblk * 4) = *(const float4*)(lrow + vblk * 4);
  }
  f32x4 o[4];
  for (int i = 0; i < 4; ++i) o[i] = f32x4{0.f, 0.f, 0.f, 0.f};
  for (int kk = 0; kk < 4; ++kk) {
    const float* apf = &lds[wave][ln * 128 + kk * 32 + quad * 8];
    short8 a;
    for (int j = 0; j < 8; ++j) a[j] = (short)f2bf(apf[j]);
    for (int nt = 0; nt < 4; ++nt) {
      short8 bfrag = *(const short8*)(fvt + (size_t)(nt * 16 + ln) * 128 +
                                      kk * 32 + quad * 8);
      o[nt] = __builtin_amdgcn_mfma_f32_16x16x32_bf16(a, bfrag, o[nt], 0, 0, 0);
    }
  }
  for (int nt = 0; nt < 4; ++nt)
    for (int reg = 0; reg < 4; ++reg) {
      int r = q0 + quad * 4 + reg;
      int c = h * 64 + nt * 16 + ln;
      OUTP[(size_t)(b * 2048 + r) * 1024 + c] = f2bf(o[nt][reg]);
    }
}

extern "C" void kernel_launch(void* const* d_in, const int* in_sizes, int n_in,
                              void* d_out, int out_size, void* d_ws,
                              size_t ws_size, hipStream_t stream) {
  const float* q = (const float*)d_in[0];
  const float* k = (const float*)d_in[1];
  const float* v = (const float*)d_in[2];
  const float* qm = (const float*)d_in[3];
  const float* km = (const float*)d_in[4];
  const float* vm = (const float*)d_in[5];
  const float* wq = (const float*)d_in[6];
  const float* bq = (const float*)d_in[7];
  const float* wk = (const float*)d_in[8];
  const float* bk = (const float*)d_in[9];
  const float* wv = (const float*)d_in[10];
  const float* bv = (const float*)d_in[11];
  const float* wo = (const float*)d_in[12];
  const float* bo = (const float*)d_in[13];
  float* out = (float*)d_out;                       // (4,2048,1024) fp32
  float* attn_out = out + (size_t)4 * 2048 * 1024;  // (4,16,2048,128) fp32

  char* ws = (char*)d_ws;
  const size_t MB = 1ull << 20;
  u16* WqT = (u16*)(ws + 0 * MB);
  u16* WkT = (u16*)(ws + 2 * MB);
  u16* WvT = (u16*)(ws + 4 * MB);
  u16* WoT = (u16*)(ws + 6 * MB);
  u16* Qws = (u16*)(ws + 8 * MB);    // 16 MB projected Q bf16
  u16* FKw = (u16*)(ws + 24 * MB);   // 1 MB (b,h,l,d)
  u16* FVTw = (u16*)(ws + 25 * MB);  // 1 MB (b,h,d,l)
  u16* OUTP = (u16*)(ws + 26 * MB);  // 16 MB pre-Wo bf16; aliased as Qc first
  u16* Qc = OUTP;                    // dead before OUTP written
  u16* Kc = (u16*)(ws + 42 * MB);
  u16* Vc = (u16*)(ws + 43 * MB);

  conv_q<<<8192, 256, 0, stream>>>(q, qm, Qc);
  conv_kv_slice<<<512, 256, 0, stream>>>(k, km, Kc);
  conv_kv_slice<<<512, 256, 0, stream>>>(v, vm, Vc);

  dim3 tb(32, 8), tg(32, 32);
  transpose_w<<<tg, tb, 0, stream>>>(wq, WqT);
  transpose_w<<<tg, tb, 0, stream>>>(wk, WkT);
  transpose_w<<<tg, tb, 0, stream>>>(wv, WvT);
  transpose_w<<<tg, tb, 0, stream>>>(wo, WoT);

  // Q projection: 8192x1024x1024, m97-style tiles
  gemm_tile<0><<<dim3(64, 8), 256, 0, stream>>>(Qc, WqT, bq, Qws, 1024, 1024);
  // K/V projections on the pre-sliced 512 rows
  gemm_bt<1><<<dim3(8, 16), 256, 0, stream>>>(Kc, WkT, bk, FKw, 1024, 1024);
  gemm_bt<2><<<dim3(8, 16), 256, 0, stream>>>(Vc, WvT, bv, FVTw, 1024, 1024);
  attn_kernel<<<dim3(64, 32), 256, 0, stream>>>(Qws, FKw, FVTw, attn_out, OUTP);
  // Output projection -> fp32 output 0
  gemm_tile<3><<<dim3(64, 8), 256, 0, stream>>>(OUTP, WoT, bo, out, 1024, 1024);
}

// Round 5
// 347.287 us; speedup vs baseline: 1.6911x; 1.0350x over previous
//
#include <hip/hip_runtime.h>

typedef unsigned short u16;
typedef unsigned int u32;
typedef __attribute__((ext_vector_type(8))) short short8;
typedef __attribute__((ext_vector_type(4))) short short4v;
typedef __attribute__((ext_vector_type(4))) float f32x4;

__device__ __forceinline__ u16 f2bf(float f) {
  union { float f; u32 u; } v; v.f = f;
  u32 u = v.u;
  u32 r = (u + 0x7fffu + ((u >> 16) & 1u)) >> 16;
  return (u16)r;
}

// async global->LDS, 16 B per lane; lds base wave-uniform, lane i -> lds+i*16B.
__device__ __forceinline__ void async_ld16(const u16* g, u16* l) {
  __builtin_amdgcn_global_load_lds(
      (const __attribute__((address_space(1))) void*)g,
      (__attribute__((address_space(3))) void*)l, 16, 0, 0);
}

// ---- q conversion: fp32 (B,S,Dm) * mask(B,S,1) -> bf16 ----
__global__ __launch_bounds__(256) void conv_q(const float* __restrict__ q,
                                              const float* __restrict__ qm,
                                              u16* __restrict__ dst) {
  int i = (blockIdx.x * 256 + threadIdx.x) * 4;
  float m = qm[i >> 10];
  float4 v = *(const float4*)(q + i);
  short4v o;
  o.x = (short)f2bf(v.x * m);
  o.y = (short)f2bf(v.y * m);
  o.z = (short)f2bf(v.z * m);
  o.w = (short)f2bf(v.w * m);
  *(short4v*)(dst + i) = o;
}

// ---- k&v slice rows [1920,2048) per batch + mask + convert (z: 0=k,1=v) ----
__global__ __launch_bounds__(256) void conv_kv_slice(
    const float* __restrict__ k, const float* __restrict__ km,
    const float* __restrict__ v, const float* __restrict__ vm,
    u16* __restrict__ kd, u16* __restrict__ vd) {
  const float* src = blockIdx.z ? v : k;
  const float* mask = blockIdx.z ? vm : km;
  u16* dst = blockIdx.z ? vd : kd;
  int i = (blockIdx.x * 256 + threadIdx.x) * 4;
  int r = i >> 10, c = i & 1023;
  size_t sr = (size_t)(r >> 7) * 2048 + 1920 + (r & 127);
  float m = mask[sr];
  float4 vv = *(const float4*)(src + sr * 1024 + c);
  short4v o;
  o.x = (short)f2bf(vv.x * m);
  o.y = (short)f2bf(vv.y * m);
  o.z = (short)f2bf(vv.z * m);
  o.w = (short)f2bf(vv.w * m);
  *(short4v*)(dst + i) = o;
}

// ---- 4 weight transposes in one launch: WT[n][k] = bf16(W[k][n]) ----
__global__ __launch_bounds__(256) void transpose_w4(
    const float* __restrict__ w0, const float* __restrict__ w1,
    const float* __restrict__ w2, const float* __restrict__ w3,
    u16* __restrict__ t0, u16* __restrict__ t1, u16* __restrict__ t2,
    u16* __restrict__ t3) {
  __shared__ u16 tile[32][33];
  int z = blockIdx.z;
  const float* W = (z == 0) ? w0 : (z == 1) ? w1 : (z == 2) ? w2 : w3;
  u16* WT = (z == 0) ? t0 : (z == 1) ? t1 : (z == 2) ? t2 : t3;
  int tx = threadIdx.x, ty = threadIdx.y;
  int x = blockIdx.x * 32 + tx;
  int y0 = blockIdx.y * 32;
  for (int i = ty; i < 32; i += 8)
    tile[i][tx] = f2bf(W[(size_t)(y0 + i) * 1024 + x]);
  __syncthreads();
  int x2 = y0 + tx;
  int r0 = blockIdx.x * 32;
  for (int i = ty; i < 32; i += 8)
    WT[(size_t)(r0 + i) * 1024 + x2] = tile[tx][i];
}

// ---- m97-style 128x128 tiled GEMM: C = A @ BT^T + bias ----
// OUTMODE 0: bf16 C[r*N+c] ; 1: bf16 FK (b,h,l,d) ; 2: bf16 FVT (b,h,d,l) ;
// 3: fp32 C[r*N+c]
template <int OUTMODE>
__global__ __launch_bounds__(256) void gemm_tile(
    const u16* __restrict__ A, const u16* __restrict__ BT,
    const float* __restrict__ bias, void* __restrict__ Cv, int N, int K) {
  __shared__ u16 As[128 * 32];  // [row][k], BK=32
  __shared__ u16 Bs[128 * 32];  // [col][k]
  const int wave = threadIdx.x >> 6, lane = threadIdx.x & 63;
  const int ln = lane & 15, quad = lane >> 4;
  const int w0 = wave & 1, w1 = wave >> 1;
  const int row0 = blockIdx.x * 128;
  const int col0 = blockIdx.y * 128;
  const int srow = lane >> 2, scol = (lane & 3) * 8;
  const u16* gA = A + (size_t)(row0 + wave * 32 + srow) * K + scol;
  const u16* gB = BT + (size_t)(col0 + wave * 32 + srow) * K + scol;
  u16* lA = &As[(wave * 32) * 32];
  u16* lB = &Bs[(wave * 32) * 32];

  f32x4 acc[4][4];
  for (int i = 0; i < 4; ++i)
    for (int j = 0; j < 4; ++j) acc[i][j] = f32x4{0.f, 0.f, 0.f, 0.f};

  for (int k0 = 0; k0 < K; k0 += 32) {
    async_ld16(gA + k0, lA);
    async_ld16(gA + (size_t)16 * K + k0, lA + 16 * 32);
    async_ld16(gB + k0, lB);
    async_ld16(gB + (size_t)16 * K + k0, lB + 16 * 32);
    __syncthreads();
    short8 af[4], bf[4];
    for (int mt = 0; mt < 4; ++mt)
      af[mt] = *(const short8*)&As[(w1 * 64 + mt * 16 + ln) * 32 + quad * 8];
    for (int nt = 0; nt < 4; ++nt)
      bf[nt] = *(const short8*)&Bs[(w0 * 64 + nt * 16 + ln) * 32 + quad * 8];
    for (int mt = 0; mt < 4; ++mt)
      for (int nt = 0; nt < 4; ++nt)
        acc[mt][nt] = __builtin_amdgcn_mfma_f32_16x16x32_bf16(af[mt], bf[nt],
                                                              acc[mt][nt], 0, 0, 0);
    __syncthreads();
  }

  for (int nt = 0; nt < 4; ++nt) {
    int c = col0 + w0 * 64 + nt * 16 + ln;
    float bval = bias ? bias[c] : 0.f;
    for (int mt = 0; mt < 4; ++mt)
      for (int reg = 0; reg < 4; ++reg) {
        int r = row0 + w1 * 64 + mt * 16 + quad * 4 + reg;
        float val = acc[mt][nt][reg] + bval;
        if (OUTMODE == 3) {
          ((float*)Cv)[(size_t)r * N + c] = val;
        } else if (OUTMODE == 0) {
          ((u16*)Cv)[(size_t)r * N + c] = f2bf(val);
        } else if (OUTMODE == 1) {
          size_t idx = ((size_t)(r >> 7) << 17) + ((size_t)(c >> 6) << 13) +
                       ((size_t)(r & 127) << 6) + (c & 63);
          ((u16*)Cv)[idx] = f2bf(val);
        } else {
          size_t idx = ((size_t)(r >> 7) << 17) + ((size_t)(c >> 6) << 13) +
                       ((size_t)(c & 63) << 7) + (r & 127);
          ((u16*)Cv)[idx] = f2bf(val);
        }
      }
  }
}

// Fused attention: per (b,h) and 16-row Q tile (4 tiles/block), no barriers.
__global__ __launch_bounds__(256) void attn_kernel(
    const u16* __restrict__ Q, const u16* __restrict__ FK,
    const u16* __restrict__ FVT, float* __restrict__ attn_out,
    u16* __restrict__ OUTP) {
  __shared__ float lds[4][16 * 132];  // P, padded row stride 132 (2-way max)
  const int wave = threadIdx.x >> 6, lane = threadIdx.x & 63;
  const int ln = lane & 15, quad = lane >> 4;
  const int bh = blockIdx.x, b = bh >> 4, h = bh & 15;
  const int q0 = blockIdx.y * 64 + wave * 16;

  const u16* qp = Q + (size_t)(b * 2048 + q0 + ln) * 1024 + h * 64 + quad * 8;
  const u16* fk = FK + ((size_t)bh << 13);
  const u16* fvt = FVT + ((size_t)bh << 13);

  f32x4 acc[8];
  for (int i = 0; i < 8; ++i) acc[i] = f32x4{0.f, 0.f, 0.f, 0.f};
  for (int ks = 0; ks < 2; ++ks) {
    short8 a = *(const short8*)(qp + ks * 32);
    for (int nt = 0; nt < 8; ++nt) {
      short8 bfrag = *(const short8*)(fk + (size_t)(nt * 16 + ln) * 64 +
                                      ks * 32 + quad * 8);
      acc[nt] = __builtin_amdgcn_mfma_f32_16x16x32_bf16(a, bfrag, acc[nt], 0, 0, 0);
    }
  }
  float mx[4] = {-3e38f, -3e38f, -3e38f, -3e38f};
  for (int nt = 0; nt < 8; ++nt) {
    int l = nt * 16 + ln;
    for (int reg = 0; reg < 4; ++reg) {
      int qg = q0 + quad * 4 + reg;
      float vv = acc[nt][reg] * 0.125f;
      if (l > qg) vv = -1e9f;
      acc[nt][reg] = vv;
      mx[reg] = fmaxf(mx[reg], vv);
    }
  }
  for (int off = 1; off < 16; off <<= 1)
    for (int reg = 0; reg < 4; ++reg)
      mx[reg] = fmaxf(mx[reg], __shfl_xor(mx[reg], off, 64));
  float sm[4] = {0.f, 0.f, 0.f, 0.f};
  for (int nt = 0; nt < 8; ++nt)
    for (int reg = 0; reg < 4; ++reg) {
      float p = __expf(acc[nt][reg] - mx[reg]);
      acc[nt][reg] = p;
      sm[reg] += p;
    }
  for (int off = 1; off < 16; off <<= 1)
    for (int reg = 0; reg < 4; ++reg) sm[reg] += __shfl_xor(sm[reg], off, 64);
  float inv[4];
  for (int reg = 0; reg < 4; ++reg) inv[reg] = 1.f / sm[reg];
  // P -> LDS (wave-local; padded stride kills 4-way write conflicts)
  for (int nt = 0; nt < 8; ++nt)
    for (int reg = 0; reg < 4; ++reg)
      lds[wave][(quad * 4 + reg) * 132 + nt * 16 + ln] = acc[nt][reg] * inv[reg];
  // attn output (fp32), vectorized from LDS
  {
    int r = lane >> 2, cb = (lane & 3) * 32;
    const float* lrow = &lds[wave][r * 132 + cb];
    float* dst = attn_out + ((size_t)bh * 2048 + q0 + r) * 128 + cb;
    for (int vblk = 0; vblk < 8; ++vblk)
      *(float4*)(dst + vblk * 4) = *(const float4*)(lrow + vblk * 4);
  }
  // PV: out(16x64) = P(16x128) @ FV(128x64)
  f32x4 o[4];
  for (int i = 0; i < 4; ++i) o[i] = f32x4{0.f, 0.f, 0.f, 0.f};
  for (int kk = 0; kk < 4; ++kk) {
    const float* apf = &lds[wave][ln * 132 + kk * 32 + quad * 8];
    short8 a;
    for (int j = 0; j < 8; ++j) a[j] = (short)f2bf(apf[j]);
    for (int nt = 0; nt < 4; ++nt) {
      short8 bfrag = *(const short8*)(fvt + (size_t)(nt * 16 + ln) * 128 +
                                      kk * 32 + quad * 8);
      o[nt] = __builtin_amdgcn_mfma_f32_16x16x32_bf16(a, bfrag, o[nt], 0, 0, 0);
    }
  }
  // stage o as bf16 in (reused) wave-local LDS, stride 72 u16 (16B-aligned rows)
  {
    u16* ot = (u16*)&lds[wave][0];
    for (int nt = 0; nt < 4; ++nt)
      for (int reg = 0; reg < 4; ++reg)
        ot[(quad * 4 + reg) * 72 + nt * 16 + ln] = f2bf(o[nt][reg]);
    int row = lane >> 2;
    u16* dst = OUTP + (size_t)(b * 2048 + q0 + row) * 1024 + h * 64;
    for (int p = 0; p < 2; ++p) {
      int col = p * 32 + (lane & 3) * 8;
      *(short8*)(dst + col) = *(const short8*)&ot[row * 72 + col];
    }
  }
}

extern "C" void kernel_launch(void* const* d_in, const int* in_sizes, int n_in,
                              void* d_out, int out_size, void* d_ws,
                              size_t ws_size, hipStream_t stream) {
  const float* q = (const float*)d_in[0];
  const float* k = (const float*)d_in[1];
  const float* v = (const float*)d_in[2];
  const float* qm = (const float*)d_in[3];
  const float* km = (const float*)d_in[4];
  const float* vm = (const float*)d_in[5];
  const float* wq = (const float*)d_in[6];
  const float* bq = (const float*)d_in[7];
  const float* wk = (const float*)d_in[8];
  const float* bk = (const float*)d_in[9];
  const float* wv = (const float*)d_in[10];
  const float* bv = (const float*)d_in[11];
  const float* wo = (const float*)d_in[12];
  const float* bo = (const float*)d_in[13];
  float* out = (float*)d_out;                       // (4,2048,1024) fp32
  float* attn_out = out + (size_t)4 * 2048 * 1024;  // (4,16,2048,128) fp32

  char* ws = (char*)d_ws;
  const size_t MB = 1ull << 20;
  u16* WqT = (u16*)(ws + 0 * MB);
  u16* WkT = (u16*)(ws + 2 * MB);
  u16* WvT = (u16*)(ws + 4 * MB);
  u16* WoT = (u16*)(ws + 6 * MB);
  u16* Qws = (u16*)(ws + 8 * MB);    // 16 MB projected Q bf16
  u16* FKw = (u16*)(ws + 24 * MB);   // 1 MB (b,h,l,d)
  u16* FVTw = (u16*)(ws + 25 * MB);  // 1 MB (b,h,d,l)
  u16* OUTP = (u16*)(ws + 26 * MB);  // 16 MB pre-Wo bf16; aliased as Qc first
  u16* Qc = OUTP;                    // dead before OUTP written
  u16* Kc = (u16*)(ws + 42 * MB);
  u16* Vc = (u16*)(ws + 43 * MB);

  conv_q<<<8192, 256, 0, stream>>>(q, qm, Qc);
  conv_kv_slice<<<dim3(512, 1, 2), 256, 0, stream>>>(k, km, v, vm, Kc, Vc);
  transpose_w4<<<dim3(32, 32, 4), dim3(32, 8), 0, stream>>>(
      wq, wk, wv, wo, WqT, WkT, WvT, WoT);

  // Q projection: 8192x1024x1024
  gemm_tile<0><<<dim3(64, 8), 256, 0, stream>>>(Qc, WqT, bq, Qws, 1024, 1024);
  // K/V projections (512 rows), tiled
  gemm_tile<1><<<dim3(4, 8), 256, 0, stream>>>(Kc, WkT, bk, FKw, 1024, 1024);
  gemm_tile<2><<<dim3(4, 8), 256, 0, stream>>>(Vc, WvT, bv, FVTw, 1024, 1024);
  attn_kernel<<<dim3(64, 32), 256, 0, stream>>>(Qws, FKw, FVTw, attn_out, OUTP);
  // Output projection -> fp32 output 0
  gemm_tile<3><<<dim3(64, 8), 256, 0, stream>>>(OUTP, WoT, bo, out, 1024, 1024);
}